// Round 4
// baseline (3110.566 us; speedup 1.0000x reference)
//
#include <hip/hip_runtime.h>
#include <stdint.h>

// MHLA_Video_Uni on MI355X (gfx950) — round 4: switch ALL intermediates + MFMAs
// from bf16 to fp16 (same 2B size, same MFMA rate, 4x lower rounding error per
// site: 2^-11 vs 2^-9). Round-3 absmax 1.175e-3 was pure accumulated-bf16-
// rounding (threshold 8.69e-4); fp16 predicts ~2.9e-4. All magnitudes verified
// << fp16 range. Structure/memory identical to round 3 (~247 MB ws).

typedef unsigned short u16;
typedef unsigned int   u32;

typedef _Float16 f16x8 __attribute__((ext_vector_type(8)));  // 8 fp16 in 4 VGPRs
typedef float    f32x4 __attribute__((ext_vector_type(4)));

#define N_TOK 18000
#define MPAD  18048
#define DIMD  1536
#define NHH   12
#define HD    128
#define CCH   64
#define NBLK  150
#define PBLK  120
#define EPSF  1e-6f

#define DEVFN static __device__ __forceinline__

DEVFN u16 f2h(float f){ _Float16 h = (_Float16)f; return __builtin_bit_cast(u16, h); }
DEVFN float h2f(u16 u){ _Float16 h = __builtin_bit_cast(_Float16, u); return (float)h; }
DEVFN int2 pack4h(float a,float b,float c,float d){
  int2 r;
  r.x = (int)((u32)f2h(a) | ((u32)f2h(b)<<16));
  r.y = (int)((u32)f2h(c) | ((u32)f2h(d)<<16));
  return r;
}
DEVFN int4 packi4(float4 lo4, float4 hi4){
  int2 lo = pack4h(lo4.x, lo4.y, lo4.z, lo4.w);
  int2 hi = pack4h(hi4.x, hi4.y, hi4.z, hi4.w);
  int4 r; r.x=lo.x; r.y=lo.y; r.z=hi.x; r.w=hi.y;
  return r;
}

// block b = (fb*5 + hb)*10 + wb ; p = (p1*6 + p2)*5 + p3 ; token = f*1500 + h*50 + w
DEVFN int tok_of(int b, int p){
  int fb = b/50, hb = (b/10)%5, wb = b%10;
  int p1 = p/30; int pr = p - p1*30; int p2 = pr/5, p3 = pr - p2*5;
  return (fb*4 + p1)*1500 + (hb*6 + p2)*50 + (wb*5 + p3);
}
DEVFN void tok_pos(int b, int p, int& tok, int& f, int& h2, int& w2){
  int fb = b/50, hb = (b/10)%5, wb = b%10;
  int p1 = p/30; int pr = p - p1*30; int p2 = pr/5, p3 = pr - p2*5;
  f = fb*4 + p1; h2 = hb*6 + p2; w2 = wb*5 + p3;
  tok = (f*30 + h2)*50 + w2;
}

// ---------------- prep kernels ----------------

__global__ void conv_w_k(const float* __restrict__ wq, const float* __restrict__ wk,
                         const float* __restrict__ wv, const float* __restrict__ wo,
                         const float* __restrict__ bq, const float* __restrict__ bk,
                         const float* __restrict__ bv,
                         u16* __restrict__ wqkvb, u16* __restrict__ wob, float* __restrict__ bqkv){
  const long i = (long)blockIdx.x*256 + threadIdx.x;
  const long idx = i*4;
  const long SQ = (long)DIMD*DIMD;
  const long WQKV = 3*SQ;
  if (idx < WQKV){
    const float* src = (idx < SQ) ? (wq + idx) : (idx < 2*SQ ? wk + (idx - SQ) : wv + (idx - 2*SQ));
    const float4 v = *(const float4*)src;
    *(int2*)(wqkvb + idx) = pack4h(v.x, v.y, v.z, v.w);
  } else if (idx < WQKV + SQ){
    const long j = idx - WQKV;
    const float4 v = *(const float4*)(wo + j);
    *(int2*)(wob + j) = pack4h(v.x, v.y, v.z, v.w);
  }
  if (i < 3*DIMD) bqkv[i] = (i < DIMD) ? bq[i] : (i < 2*DIMD ? bk[i - DIMD] : bv[i - 2*DIMD]);
}

// W_BLK: centers over meshgrid(3,5,10); mat = 1 - d/dmax (fp64, dmax = sqrt(101)); col-normalized.
__global__ void wblk_k(float* __restrict__ wblk){
  __shared__ double cs[NBLK];
  const int t = threadIdx.x;
  const double dmax = sqrt(101.0);
  if (t < NBLK){
    const int fi = t/50, hi = (t/10)%5, wi = t%10;
    double s = 0.0;
    for (int o = 0; o < NBLK; o++){
      const int fo = o/50, ho = (o/10)%5, wo = o%10;
      const int df = fo-fi, dh = ho-hi, dw = wo-wi;
      s += 1.0 - sqrt((double)(df*df + dh*dh + dw*dw))/dmax;
    }
    cs[t] = s;
  }
  __syncthreads();
  for (int idx = t; idx < NBLK*NBLK; idx += 256){
    const int o = idx/NBLK, i = idx%NBLK;
    const int fo = o/50, ho = (o/10)%5, wo = o%10;
    const int fi = i/50, hi = (i/10)%5, wi = i%10;
    const int df = fo-fi, dh = ho-hi, dw = wo-wi;
    const double v = 1.0 - sqrt((double)(df*df + dh*dh + dw*dw))/dmax;
    wblk[idx] = (float)(v / cs[i]);
  }
}

// ---------------- GEMM1: C[row,col] = sum_k A_f32[row,k]*B_f16[col,k] + bias[col] ----------------
// A: fp32 [N_TOK x K] (rows >= N_TOK read as 0), B: [DIMD x K] fp16, C: [MPAD x DIMD] fp16.
__global__ __launch_bounds__(256) void gemm_af32(const float* __restrict__ A, const u16* __restrict__ B,
                                                 const float* __restrict__ bias, u16* __restrict__ C, int K){
  __shared__ u16 As[128*32];
  __shared__ u16 Bs[128*32];
  const int t = threadIdx.x;
  const int bn = blockIdx.x, bm = blockIdx.y;
  const long row0 = (long)bm*128; const int col0 = bn*128;
  const int wave = t>>6, lane = t&63, lr = lane&15, quad = lane>>4;
  const int wm = (wave&1)*64, wn = (wave>>1)*64;
  f32x4 acc[4][4] = {};

  const int c0 = t, c1 = t + 256;              // 16B(f16) chunk ids; row=c>>2, koff=(c&3)*8
  const long r0r = row0 + (c0>>2), r1r = row0 + (c1>>2);
  const bool ok0 = r0r < N_TOK, ok1 = r1r < N_TOK;
  const float* Ap0 = A + r0r*K + (c0&3)*8;
  const float* Ap1 = A + r1r*K + (c1&3)*8;
  const u16* Bp0 = B + (long)(col0 + (c0>>2))*K + (c0&3)*8;
  const u16* Bp1 = B + (long)(col0 + (c1>>2))*K + (c1&3)*8;
  const float4 z4 = make_float4(0.f,0.f,0.f,0.f);
  float4 a00 = ok0 ? *(const float4*)Ap0     : z4;
  float4 a01 = ok0 ? *(const float4*)(Ap0+4) : z4;
  float4 a10 = ok1 ? *(const float4*)Ap1     : z4;
  float4 a11 = ok1 ? *(const float4*)(Ap1+4) : z4;
  int4 rb0 = *(const int4*)Bp0, rb1 = *(const int4*)Bp1;

  for (int k0 = 0; k0 < K; k0 += 32){
    __syncthreads();
    *(int4*)&As[c0*8] = packi4(a00, a01);
    *(int4*)&As[c1*8] = packi4(a10, a11);
    *(int4*)&Bs[c0*8] = rb0; *(int4*)&Bs[c1*8] = rb1;
    __syncthreads();
    if (k0 + 32 < K){
      a00 = ok0 ? *(const float4*)(Ap0 + k0+32)   : z4;
      a01 = ok0 ? *(const float4*)(Ap0 + k0+36)   : z4;
      a10 = ok1 ? *(const float4*)(Ap1 + k0+32)   : z4;
      a11 = ok1 ? *(const float4*)(Ap1 + k0+36)   : z4;
      rb0 = *(const int4*)(Bp0 + k0+32); rb1 = *(const int4*)(Bp1 + k0+32);
    }
    const f16x8* As8 = (const f16x8*)As;
    const f16x8* Bs8 = (const f16x8*)Bs;
    f16x8 aF[4], bF[4];
#pragma unroll
    for (int mt = 0; mt < 4; mt++) aF[mt] = As8[(wm + mt*16 + lr)*4 + quad];
#pragma unroll
    for (int nt = 0; nt < 4; nt++) bF[nt] = Bs8[(wn + nt*16 + lr)*4 + quad];
#pragma unroll
    for (int mt = 0; mt < 4; mt++)
#pragma unroll
      for (int nt = 0; nt < 4; nt++)
        acc[mt][nt] = __builtin_amdgcn_mfma_f32_16x16x32_f16(aF[mt], bF[nt], acc[mt][nt], 0, 0, 0);
  }
#pragma unroll
  for (int mt = 0; mt < 4; mt++)
#pragma unroll
    for (int nt = 0; nt < 4; nt++){
      const int colb = col0 + wn + nt*16 + lr;
      const float bb = bias[colb];
#pragma unroll
      for (int r = 0; r < 4; r++){
        const long rr = row0 + wm + mt*16 + quad*4 + r;   // C/D: col=lane&15, row=quad*4+reg
        C[rr*DIMD + colb] = f2h(acc[mt][nt][r] + bb);     // pad rows get bias values (harmless)
      }
    }
}

// ---------------- GEMM2 (final): A f16 [MPAD x K], C fp32 = d_out, rows < N_TOK only ----------------
__global__ __launch_bounds__(256) void gemm_bt(const u16* __restrict__ A, const u16* __restrict__ B,
                                               const float* __restrict__ bias, float* __restrict__ C, int K){
  __shared__ u16 As[128*32];
  __shared__ u16 Bs[128*32];
  const int t = threadIdx.x;
  const int bn = blockIdx.x, bm = blockIdx.y;
  const long row0 = (long)bm*128; const int col0 = bn*128;
  const int wave = t>>6, lane = t&63, lr = lane&15, quad = lane>>4;
  const int wm = (wave&1)*64, wn = (wave>>1)*64;
  f32x4 acc[4][4] = {};

  const int c0 = t, c1 = t + 256;
  const u16* Ap0 = A + (row0 + (c0>>2))*K + (c0&3)*8;
  const u16* Ap1 = A + (row0 + (c1>>2))*K + (c1&3)*8;
  const u16* Bp0 = B + (long)(col0 + (c0>>2))*K + (c0&3)*8;
  const u16* Bp1 = B + (long)(col0 + (c1>>2))*K + (c1&3)*8;
  int4 ra0 = *(const int4*)Ap0, ra1 = *(const int4*)Ap1;
  int4 rb0 = *(const int4*)Bp0, rb1 = *(const int4*)Bp1;

  for (int k0 = 0; k0 < K; k0 += 32){
    __syncthreads();
    *(int4*)&As[c0*8] = ra0; *(int4*)&As[c1*8] = ra1;
    *(int4*)&Bs[c0*8] = rb0; *(int4*)&Bs[c1*8] = rb1;
    __syncthreads();
    if (k0 + 32 < K){
      ra0 = *(const int4*)(Ap0 + k0+32); ra1 = *(const int4*)(Ap1 + k0+32);
      rb0 = *(const int4*)(Bp0 + k0+32); rb1 = *(const int4*)(Bp1 + k0+32);
    }
    const f16x8* As8 = (const f16x8*)As;
    const f16x8* Bs8 = (const f16x8*)Bs;
    f16x8 aF[4], bF[4];
#pragma unroll
    for (int mt = 0; mt < 4; mt++) aF[mt] = As8[(wm + mt*16 + lr)*4 + quad];
#pragma unroll
    for (int nt = 0; nt < 4; nt++) bF[nt] = Bs8[(wn + nt*16 + lr)*4 + quad];
#pragma unroll
    for (int mt = 0; mt < 4; mt++)
#pragma unroll
      for (int nt = 0; nt < 4; nt++)
        acc[mt][nt] = __builtin_amdgcn_mfma_f32_16x16x32_f16(aF[mt], bF[nt], acc[mt][nt], 0, 0, 0);
  }
#pragma unroll
  for (int mt = 0; mt < 4; mt++)
#pragma unroll
    for (int nt = 0; nt < 4; nt++){
      const int colb = col0 + wn + nt*16 + lr;
      const float bb = bias[colb];
#pragma unroll
      for (int r = 0; r < 4; r++){
        const long rr = row0 + wm + mt*16 + quad*4 + r;
        if (rr < N_TOK) C[rr*DIMD + colb] = acc[mt][nt][r] + bb;   // fp32 output
      }
    }
}

// ---------------- rmsnorm + relu + eps, in-place on qb and kb ----------------
__global__ __launch_bounds__(256) void norm_k(u16* __restrict__ qb, u16* __restrict__ kb,
                                              const float* __restrict__ nqw, const float* __restrict__ nkw){
  __shared__ float red[4];
  __shared__ float s_scale;
  const int n = blockIdx.x, t = threadIdx.x, lane = t&63, wv = t>>6;
  u16* bufs[2]; bufs[0] = qb; bufs[1] = kb;
  const float* wgts[2]; wgts[0] = nqw; wgts[1] = nkw;
  for (int pass = 0; pass < 2; pass++){
    u16* row = bufs[pass] + (long)n*DIMD;
    const float* wgt = wgts[pass];
    float v[6];
    float ssq = 0.f;
#pragma unroll
    for (int i = 0; i < 6; i++){ v[i] = h2f(row[t + i*256]); ssq += v[i]*v[i]; }
#pragma unroll
    for (int o = 32; o > 0; o >>= 1) ssq += __shfl_down(ssq, o);
    if (lane == 0) red[wv] = ssq;
    __syncthreads();
    if (t == 0) s_scale = rsqrtf((red[0]+red[1]+red[2]+red[3])/(float)DIMD + EPSF);
    __syncthreads();
    const float sc = s_scale;
#pragma unroll
    for (int i = 0; i < 6; i++){
      float r = fmaxf(v[i]*sc*wgt[t + i*256], 0.f) + EPSF;
      row[t + i*256] = f2h(r);
    }
    __syncthreads();
  }
}

// ---------------- ksum[h,b,d] = sum_p k_normed ----------------
__global__ __launch_bounds__(128) void ksum_k(const u16* __restrict__ kb, float* __restrict__ ksum){
  const int hb = blockIdx.x; const int h = hb/NBLK, b = hb%NBLK; const int d = threadIdx.x;
  float s = 0.f;
  for (int p = 0; p < PBLK; p++)
    s += h2f(kb[(long)tok_of(b, p)*DIMD + h*HD + d]);
  ksum[(long)hb*HD + d] = s;
}

// ---------------- qk[h,b,p] = q_normed . ksum ----------------
__global__ __launch_bounds__(128) void qk_k(const u16* __restrict__ qb, const float* __restrict__ ksum,
                                            float* __restrict__ qk){
  __shared__ float ks[HD];
  const int hb = blockIdx.x, h = hb/NBLK, b = hb%NBLK, t = threadIdx.x;
  ks[t] = ksum[(long)hb*HD + t];
  __syncthreads();
  if (t < PBLK){
    const u16* row = qb + (long)tok_of(b, t)*DIMD + h*HD;
    float s = 0.f;
#pragma unroll
    for (int d8 = 0; d8 < 16; d8++){
      int4 v4 = *(const int4*)(row + d8*8);
      const u16* pv = (const u16*)&v4;
#pragma unroll
      for (int j = 0; j < 8; j++) s += h2f(pv[j])*ks[d8*8 + j];
    }
    qk[(long)hb*PBLK + t] = s;
  }
}

// ---------------- norm[h,o,p] = sum_i W[o,i]*qk[h,i,p] + eps ----------------
__global__ __launch_bounds__(128) void mixqk_k(const float* __restrict__ qk, const float* __restrict__ wblk,
                                               float* __restrict__ nrm){
  const int ho = blockIdx.x, h = ho/NBLK, o = ho%NBLK, t = threadIdx.x;
  if (t >= PBLK) return;
  float s = 0.f;
  for (int i = 0; i < NBLK; i++) s += wblk[o*NBLK + i]*qk[((long)h*NBLK + i)*PBLK + t];
  nrm[(long)ho*PBLK + t] = s + EPSF;
}

// ---------------- kv1[h,b][e*128+d] = sum_p rope(K)[p,d]*V[p,e]  (RoPE fused in staging) ----------------
__global__ __launch_bounds__(256) void kv_k(const u16* __restrict__ kb, const u16* __restrict__ vb,
                                            const float* __restrict__ fcos, const float* __restrict__ fsin,
                                            u16* __restrict__ kv1){
  __shared__ u16 Ap[4][128][32];   // A = V^T : Ap[p>>5][e][p&31] = V[p,e]
  __shared__ u16 Bp[4][128][32];   // B = Kr^T: Bp[p>>5][d][p&31] = rope(K)[p,d]
  const int hb = blockIdx.x, h = hb/NBLK, b = hb%NBLK, t = threadIdx.x;
  for (int idx = t; idx < 128*64; idx += 256){
    const int p = idx>>6, cc = idx&63;
    u16 v0=0, v1=0, r0=0, r1=0;
    if (p < PBLK){
      int tok, f, hh, ww; tok_pos(b, p, tok, f, hh, ww);
      const long tb = (long)tok*DIMD + h*HD + 2*cc;
      const u32 vv = *(const u32*)&vb[tb];
      const u32 kk = *(const u32*)&kb[tb];
      const int pos = (cc < 22) ? f : (cc < 43 ? hh : ww);
      const float cv = fcos[pos*CCH + cc], sv = fsin[pos*CCH + cc];
      const float x0 = h2f((u16)kk), x1 = h2f((u16)(kk>>16));
      v0 = (u16)vv; v1 = (u16)(vv>>16);
      r0 = f2h(x0*cv - x1*sv); r1 = f2h(x0*sv + x1*cv);
    }
    const int kp = p>>5, j = p&31;
    Ap[kp][2*cc][j] = v0; Ap[kp][2*cc+1][j] = v1;
    Bp[kp][2*cc][j] = r0; Bp[kp][2*cc+1][j] = r1;
  }
  __syncthreads();
  const int wave = t>>6, lane = t&63, lr = lane&15, quad = lane>>4;
  const int wm = (wave&1)*64, wn = (wave>>1)*64;
  f32x4 acc[4][4] = {};
#pragma unroll
  for (int kp = 0; kp < 4; kp++){
    f16x8 aF[4], bF[4];
#pragma unroll
    for (int mt = 0; mt < 4; mt++) aF[mt] = *(const f16x8*)&Ap[kp][wm + mt*16 + lr][quad*8];
#pragma unroll
    for (int nt = 0; nt < 4; nt++) bF[nt] = *(const f16x8*)&Bp[kp][wn + nt*16 + lr][quad*8];
#pragma unroll
    for (int mt = 0; mt < 4; mt++)
#pragma unroll
      for (int nt = 0; nt < 4; nt++)
        acc[mt][nt] = __builtin_amdgcn_mfma_f32_16x16x32_f16(aF[mt], bF[nt], acc[mt][nt], 0, 0, 0);
  }
  u16* outp = kv1 + (long)hb*HD*HD;   // D[e,d] stored at [e*128+d] == kv[d,e]
#pragma unroll
  for (int mt = 0; mt < 4; mt++)
#pragma unroll
    for (int nt = 0; nt < 4; nt++)
#pragma unroll
      for (int r = 0; r < 4; r++)
        outp[(wm + mt*16 + quad*4 + r)*HD + wn + nt*16 + lr] = f2h(acc[mt][nt][r]);
}

// ---------------- kv2[h,o,:] = sum_i W[o,i]*kv1[h,i,:] ----------------
__global__ __launch_bounds__(256) void mix_k(const u16* __restrict__ kv1, const float* __restrict__ wblk,
                                             u16* __restrict__ kv2){
  __shared__ float X[NBLK][64];
  const int h = blockIdx.x >> 8, chunk = blockIdx.x & 255, t = threadIdx.x;
  const long base = (long)h*NBLK*HD*HD + chunk*64;
  for (int idx = t; idx < NBLK*64; idx += 256){
    const int i = idx>>6, de = idx&63;
    X[i][de] = h2f(kv1[base + (long)i*HD*HD + de]);
  }
  __syncthreads();
  const int de = t&63, og = t>>6;
  for (int o = og; o < NBLK; o += 4){
    const float* wr = wblk + o*NBLK;
    float s = 0.f;
    for (int i = 0; i < NBLK; i++) s += wr[i]*X[i][de];
    kv2[base + (long)o*HD*HD + de] = f2h(s);
  }
}

// ---------------- attn: Out[p,e] = (sum_d rope(Q)[p,d]*kv[d,e]) / norm[p]  (RoPE fused) ----------------
// aout == qb is safe: block (h,o) reads exactly the region it writes (rows of block o,
// cols of head h); reads complete before __syncthreads; regions disjoint across blocks.
__global__ __launch_bounds__(256) void attn_k(const u16* __restrict__ qb, const u16* __restrict__ kv2,
                                              const float* __restrict__ fcos, const float* __restrict__ fsin,
                                              const float* __restrict__ nrm, u16* __restrict__ aout){
  __shared__ u16 Ap[4][128][32];   // A: Ap[d>>5][p][d&31] = rope(Q)[p,d]
  __shared__ u16 Bp[4][128][32];   // B: Bp[d>>5][e][d&31] = kv[d,e]  (kv2 stored [e*128+d])
  const int ho = blockIdx.x, h = ho/NBLK, o = ho%NBLK, t = threadIdx.x;
  for (int idx = t; idx < 128*64; idx += 256){
    const int p = idx>>6, cc = idx&63;
    u32 w = 0;
    if (p < PBLK){
      int tok, f, hh, ww; tok_pos(o, p, tok, f, hh, ww);
      const u32 qq = *(const u32*)&qb[(long)tok*DIMD + h*HD + 2*cc];
      const int pos = (cc < 22) ? f : (cc < 43 ? hh : ww);
      const float cv = fcos[pos*CCH + cc], sv = fsin[pos*CCH + cc];
      const float x0 = h2f((u16)qq), x1 = h2f((u16)(qq>>16));
      w = (u32)f2h(x0*cv - x1*sv) | ((u32)f2h(x0*sv + x1*cv) << 16);
    }
    *(u32*)&Ap[(2*cc)>>5][p][(2*cc)&31] = w;
  }
  const u16* kv2p = kv2 + (long)ho*HD*HD;
  for (int idx = t; idx < 128*16; idx += 256){
    const int e = idx>>4, d8 = (idx&15)*8;
    int4 vv = *(const int4*)&kv2p[e*HD + d8];
    *(int4*)&Bp[d8>>5][e][d8&31] = vv;
  }
  __syncthreads();
  const int wave = t>>6, lane = t&63, lr = lane&15, quad = lane>>4;
  const int wm = (wave&1)*64, wn = (wave>>1)*64;
  f32x4 acc[4][4] = {};
#pragma unroll
  for (int kp = 0; kp < 4; kp++){
    f16x8 aF[4], bF[4];
#pragma unroll
    for (int mt = 0; mt < 4; mt++) aF[mt] = *(const f16x8*)&Ap[kp][wm + mt*16 + lr][quad*8];
#pragma unroll
    for (int nt = 0; nt < 4; nt++) bF[nt] = *(const f16x8*)&Bp[kp][wn + nt*16 + lr][quad*8];
#pragma unroll
    for (int mt = 0; mt < 4; mt++)
#pragma unroll
      for (int nt = 0; nt < 4; nt++)
        acc[mt][nt] = __builtin_amdgcn_mfma_f32_16x16x32_f16(aF[mt], bF[nt], acc[mt][nt], 0, 0, 0);
  }
#pragma unroll
  for (int mt = 0; mt < 4; mt++)
#pragma unroll
    for (int r = 0; r < 4; r++){
      const int p = wm + mt*16 + quad*4 + r;
      if (p >= PBLK) continue;
      const float inv = 1.0f / nrm[(long)ho*PBLK + p];
      const long tb = (long)tok_of(o, p)*DIMD + h*HD;
#pragma unroll
      for (int nt = 0; nt < 4; nt++)
        aout[tb + wn + nt*16 + lr] = f2h(acc[mt][nt][r]*inv);
    }
}

// ---------------- launch ----------------
extern "C" void kernel_launch(void* const* d_in, const int* in_sizes, int n_in,
                              void* d_out, int out_size, void* d_ws, size_t ws_size,
                              hipStream_t stream){
  const float* x    = (const float*)d_in[0];
  const float* fcos = (const float*)d_in[3];
  const float* fsin = (const float*)d_in[4];
  const float* wq   = (const float*)d_in[5];
  const float* bq   = (const float*)d_in[6];
  const float* wk   = (const float*)d_in[7];
  const float* bk   = (const float*)d_in[8];
  const float* wv   = (const float*)d_in[9];
  const float* bv   = (const float*)d_in[10];
  const float* wo   = (const float*)d_in[11];
  const float* bo   = (const float*)d_in[12];
  const float* nqw  = (const float*)d_in[13];
  const float* nkw  = (const float*)d_in[14];
  float* out = (float*)d_out;   // reference output dtype is fp32
  (void)in_sizes; (void)n_in; (void)out_size; (void)ws_size;

  char* ws = (char*)d_ws; size_t off = 0;
  auto alloc = [&](size_t b)->void*{ void* p = ws + off; off += (b + 255) & ~(size_t)255; return p; };
  const size_t SQ = (size_t)DIMD*DIMD;
  u16*   wqkvb = (u16*)  alloc(3*SQ*2);                     // 14.2 MB (fp16)
  u16*   wob   = (u16*)  alloc(SQ*2);                       //  4.7 MB (fp16)
  float* bqkv  = (float*)alloc((size_t)3*DIMD*4);
  float* wblk  = (float*)alloc((size_t)NBLK*NBLK*4);
  u16*   qb    = (u16*)  alloc((size_t)MPAD*DIMD*2);        // 55.4 MB (later: attn output)
  u16*   kb    = (u16*)  alloc((size_t)MPAD*DIMD*2);        // 55.4 MB (dead after kv_k)
  u16*   vb    = (u16*)  alloc((size_t)MPAD*DIMD*2);        // 55.4 MB (dead after kv_k)
  u16*   kv1   = (u16*)  alloc((size_t)NHH*NBLK*HD*HD*2);   // 59.0 MB
  float* ksum  = (float*)alloc((size_t)NHH*NBLK*HD*4);      //  0.9 MB
  float* qk    = (float*)alloc((size_t)NHH*NBLK*PBLK*4);    //  0.9 MB
  float* nrm   = (float*)alloc((size_t)NHH*NBLK*PBLK*4);    //  0.9 MB
  u16*   kv2   = kb;    // 59.0 MB alias over [kb..vb) — both dead before mix_k writes
  // total fresh: ~247 MB

  conv_w_k<<<9216, 256, 0, stream>>>(wq, wk, wv, wo, bq, bk, bv, wqkvb, wob, bqkv);
  wblk_k<<<1, 256, 0, stream>>>(wblk);
  gemm_af32<<<dim3(DIMD/128, MPAD/128), 256, 0, stream>>>(x, wqkvb,        bqkv,          qb, DIMD);
  gemm_af32<<<dim3(DIMD/128, MPAD/128), 256, 0, stream>>>(x, wqkvb + SQ,   bqkv + DIMD,   kb, DIMD);
  gemm_af32<<<dim3(DIMD/128, MPAD/128), 256, 0, stream>>>(x, wqkvb + 2*SQ, bqkv + 2*DIMD, vb, DIMD);
  norm_k<<<N_TOK, 256, 0, stream>>>(qb, kb, nqw, nkw);
  ksum_k<<<NHH*NBLK, 128, 0, stream>>>(kb, ksum);
  qk_k<<<NHH*NBLK, 128, 0, stream>>>(qb, ksum, qk);
  mixqk_k<<<NHH*NBLK, 128, 0, stream>>>(qk, wblk, nrm);
  kv_k<<<NHH*NBLK, 256, 0, stream>>>(kb, vb, fcos, fsin, kv1);
  mix_k<<<NHH*256, 256, 0, stream>>>(kv1, wblk, kv2);
  attn_k<<<NHH*NBLK, 256, 0, stream>>>(qb, kv2, fcos, fsin, nrm, qb);  // output aliases qb
  gemm_bt<<<dim3(DIMD/128, MPAD/128), 256, 0, stream>>>(qb, wob, bo, out, DIMD);
}

// Round 5
// 1524.051 us; speedup vs baseline: 2.0410x; 2.0410x over previous
//
#include <hip/hip_runtime.h>
#include <stdint.h>

// MHLA_Video_Uni on MI355X (gfx950) — round 5: GEMM restructure per m97 recipe.
//  * QKV fused into ONE GEMM (N=4608), A pre-converted to f16 once (conv_x_k).
//  * Both big GEMMs stage via __builtin_amdgcn_global_load_lds width=16
//    (measured 517->874 TF on this structure) — removes the register-prefetch
//    vmcnt(0) serialization that left round 4 at 5% MfmaUtil / 672 us each.
//  * xh aliases kv1 (dead by the time kv_k writes) — ws stays ~247 MB.
// Round-4 baseline: PASS, absmax 2.44e-4, dur 3110 us (3x gemm_af32 = 2016 us).

typedef unsigned short u16;
typedef unsigned int   u32;

typedef _Float16 f16x8 __attribute__((ext_vector_type(8)));  // 8 fp16 in 4 VGPRs
typedef float    f32x4 __attribute__((ext_vector_type(4)));

#define N_TOK 18000
#define MPAD  18048
#define DIMD  1536
#define NHH   12
#define HD    128
#define CCH   64
#define QKVN  4608
#define NBLK  150
#define PBLK  120
#define EPSF  1e-6f

#define DEVFN static __device__ __forceinline__
#define AS1 __attribute__((address_space(1)))
#define AS3 __attribute__((address_space(3)))

DEVFN u16 f2h(float f){ _Float16 h = (_Float16)f; return __builtin_bit_cast(u16, h); }
DEVFN float h2f(u16 u){ _Float16 h = __builtin_bit_cast(_Float16, u); return (float)h; }
DEVFN int2 pack4h(float a,float b,float c,float d){
  int2 r;
  r.x = (int)((u32)f2h(a) | ((u32)f2h(b)<<16));
  r.y = (int)((u32)f2h(c) | ((u32)f2h(d)<<16));
  return r;
}
DEVFN int4 packi4(float4 lo4, float4 hi4){
  int2 lo = pack4h(lo4.x, lo4.y, lo4.z, lo4.w);
  int2 hi = pack4h(hi4.x, hi4.y, hi4.z, hi4.w);
  int4 r; r.x=lo.x; r.y=lo.y; r.z=hi.x; r.w=hi.y;
  return r;
}

// async global->LDS, 16B per lane. LDS dst must be wave-uniform base + lane*16.
DEVFN void gl_lds16(const u16* g, u16* l){
  __builtin_amdgcn_global_load_lds((const AS1 void*)g, (AS3 void*)l, 16, 0, 0);
}

// block b = (fb*5 + hb)*10 + wb ; p = (p1*6 + p2)*5 + p3 ; token = f*1500 + h*50 + w
DEVFN int tok_of(int b, int p){
  int fb = b/50, hb = (b/10)%5, wb = b%10;
  int p1 = p/30; int pr = p - p1*30; int p2 = pr/5, p3 = pr - p2*5;
  return (fb*4 + p1)*1500 + (hb*6 + p2)*50 + (wb*5 + p3);
}
DEVFN void tok_pos(int b, int p, int& tok, int& f, int& h2, int& w2){
  int fb = b/50, hb = (b/10)%5, wb = b%10;
  int p1 = p/30; int pr = p - p1*30; int p2 = pr/5, p3 = pr - p2*5;
  f = fb*4 + p1; h2 = hb*6 + p2; w2 = wb*5 + p3;
  tok = (f*30 + h2)*50 + w2;
}

// ---------------- prep kernels ----------------

__global__ void conv_x_k(const float* __restrict__ x, u16* __restrict__ xh){
  const long i = ((long)blockIdx.x*256 + threadIdx.x)*8;
  if (i >= (long)MPAD*DIMD) return;
  if (i < (long)N_TOK*DIMD){
    const float4 a = *(const float4*)(x + i);
    const float4 b = *(const float4*)(x + i + 4);
    *(int4*)(xh + i) = packi4(a, b);
  } else {
    *(int4*)(xh + i) = make_int4(0,0,0,0);   // zero-pad rows 18000..18047
  }
}

__global__ void conv_w_k(const float* __restrict__ wq, const float* __restrict__ wk,
                         const float* __restrict__ wv, const float* __restrict__ wo,
                         const float* __restrict__ bq, const float* __restrict__ bk,
                         const float* __restrict__ bv,
                         u16* __restrict__ wqkvb, u16* __restrict__ wob, float* __restrict__ bqkv){
  const long i = (long)blockIdx.x*256 + threadIdx.x;
  const long idx = i*4;
  const long SQ = (long)DIMD*DIMD;
  const long WQKV = 3*SQ;
  if (idx < WQKV){
    const float* src = (idx < SQ) ? (wq + idx) : (idx < 2*SQ ? wk + (idx - SQ) : wv + (idx - 2*SQ));
    const float4 v = *(const float4*)src;
    *(int2*)(wqkvb + idx) = pack4h(v.x, v.y, v.z, v.w);
  } else if (idx < WQKV + SQ){
    const long j = idx - WQKV;
    const float4 v = *(const float4*)(wo + j);
    *(int2*)(wob + j) = pack4h(v.x, v.y, v.z, v.w);
  }
  if (i < 3*DIMD) bqkv[i] = (i < DIMD) ? bq[i] : (i < 2*DIMD ? bk[i - DIMD] : bv[i - 2*DIMD]);
}

// W_BLK: centers over meshgrid(3,5,10); mat = 1 - d/dmax (fp64, dmax = sqrt(101)); col-normalized.
__global__ void wblk_k(float* __restrict__ wblk){
  __shared__ double cs[NBLK];
  const int t = threadIdx.x;
  const double dmax = sqrt(101.0);
  if (t < NBLK){
    const int fi = t/50, hi = (t/10)%5, wi = t%10;
    double s = 0.0;
    for (int o = 0; o < NBLK; o++){
      const int fo = o/50, ho = (o/10)%5, wo = o%10;
      const int df = fo-fi, dh = ho-hi, dw = wo-wi;
      s += 1.0 - sqrt((double)(df*df + dh*dh + dw*dw))/dmax;
    }
    cs[t] = s;
  }
  __syncthreads();
  for (int idx = t; idx < NBLK*NBLK; idx += 256){
    const int o = idx/NBLK, i = idx%NBLK;
    const int fo = o/50, ho = (o/10)%5, wo = o%10;
    const int fi = i/50, hi = (i/10)%5, wi = i%10;
    const int df = fo-fi, dh = ho-hi, dw = wo-wi;
    const double v = 1.0 - sqrt((double)(df*df + dh*dh + dw*dw))/dmax;
    wblk[idx] = (float)(v / cs[i]);
  }
}

// ---------------- fused QKV GEMM: C[row, gcol] = sum_k xh[row,k]*Wqkv[gcol,k] + b[gcol] ----------------
// A: f16 [MPAD x 1536] (pad rows zero), B: [4608 x 1536] f16. Output split to qb/kb/vb by gcol/1536.
// m97-style: global_load_lds(16B) staging, 2 barriers per K-tile; barrier's vmcnt drain publishes LDS.
__global__ __launch_bounds__(256) void gemm_qkv(const u16* __restrict__ A, const u16* __restrict__ B,
                                                const float* __restrict__ bias,
                                                u16* __restrict__ qb, u16* __restrict__ kb, u16* __restrict__ vb){
  __shared__ u16 As[128*32];
  __shared__ u16 Bs[128*32];
  const int t = threadIdx.x;
  const int bn = blockIdx.x, bm = blockIdx.y;
  const long row0 = (long)bm*128; const int gcol0 = bn*128;
  const int K = DIMD;
  const int wave = t>>6, lane = t&63, lr = lane&15, quad = lane>>4;
  const int wm = (wave&1)*64, wn = (wave>>1)*64;
  f32x4 acc[4][4] = {};

  // staging chunks: c in [0,512); row=c>>2, koff=(c&3)*8 halves; LDS offset = c*8 halves (lane*16B contiguous)
  const int c0 = t, c1 = t + 256;
  const u16* ga0 = A + (row0 + (c0>>2))*K + (c0&3)*8;
  const u16* ga1 = A + (row0 + (c1>>2))*K + (c1&3)*8;
  const u16* gb0 = B + (long)(gcol0 + (c0>>2))*K + (c0&3)*8;
  const u16* gb1 = B + (long)(gcol0 + (c1>>2))*K + (c1&3)*8;
  u16* la0 = As + c0*8; u16* la1 = As + c1*8;
  u16* lb0 = Bs + c0*8; u16* lb1 = Bs + c1*8;

  for (int k0 = 0; k0 < K; k0 += 32){
    gl_lds16(ga0 + k0, la0); gl_lds16(ga1 + k0, la1);
    gl_lds16(gb0 + k0, lb0); gl_lds16(gb1 + k0, lb1);
    __syncthreads();                       // vmcnt(0) drain + publish
    const f16x8* As8 = (const f16x8*)As;
    const f16x8* Bs8 = (const f16x8*)Bs;
    f16x8 aF[4], bF[4];
#pragma unroll
    for (int mt = 0; mt < 4; mt++) aF[mt] = As8[(wm + mt*16 + lr)*4 + quad];
#pragma unroll
    for (int nt = 0; nt < 4; nt++) bF[nt] = Bs8[(wn + nt*16 + lr)*4 + quad];
#pragma unroll
    for (int mt = 0; mt < 4; mt++)
#pragma unroll
      for (int nt = 0; nt < 4; nt++)
        acc[mt][nt] = __builtin_amdgcn_mfma_f32_16x16x32_f16(aF[mt], bF[nt], acc[mt][nt], 0, 0, 0);
    __syncthreads();                       // LDS free before next tile's loads
  }

  const int which = bn/12;                 // 0:q 1:k 2:v
  u16* dst = (which == 0) ? qb : (which == 1 ? kb : vb);
  const int col0l = (bn - which*12)*128;
#pragma unroll
  for (int mt = 0; mt < 4; mt++)
#pragma unroll
    for (int nt = 0; nt < 4; nt++){
      const int gcolb = gcol0 + wn + nt*16 + lr;
      const float bb = bias[gcolb];
      const int colb = col0l + wn + nt*16 + lr;
#pragma unroll
      for (int r = 0; r < 4; r++){
        const long rr = row0 + wm + mt*16 + quad*4 + r;   // C/D: col=lane&15, row=quad*4+reg
        if (rr < N_TOK) dst[rr*DIMD + colb] = f2h(acc[mt][nt][r] + bb);
      }
    }
}

// ---------------- final GEMM: A f16 [MPAD x K], C fp32 = d_out (rows < N_TOK) ----------------
__global__ __launch_bounds__(256) void gemm_bt(const u16* __restrict__ A, const u16* __restrict__ B,
                                               const float* __restrict__ bias, float* __restrict__ C, int K){
  __shared__ u16 As[128*32];
  __shared__ u16 Bs[128*32];
  const int t = threadIdx.x;
  const int bn = blockIdx.x, bm = blockIdx.y;
  const long row0 = (long)bm*128; const int col0 = bn*128;
  const int wave = t>>6, lane = t&63, lr = lane&15, quad = lane>>4;
  const int wm = (wave&1)*64, wn = (wave>>1)*64;
  f32x4 acc[4][4] = {};

  const int c0 = t, c1 = t + 256;
  const u16* ga0 = A + (row0 + (c0>>2))*K + (c0&3)*8;
  const u16* ga1 = A + (row0 + (c1>>2))*K + (c1&3)*8;
  const u16* gb0 = B + (long)(col0 + (c0>>2))*K + (c0&3)*8;
  const u16* gb1 = B + (long)(col0 + (c1>>2))*K + (c1&3)*8;
  u16* la0 = As + c0*8; u16* la1 = As + c1*8;
  u16* lb0 = Bs + c0*8; u16* lb1 = Bs + c1*8;

  for (int k0 = 0; k0 < K; k0 += 32){
    gl_lds16(ga0 + k0, la0); gl_lds16(ga1 + k0, la1);
    gl_lds16(gb0 + k0, lb0); gl_lds16(gb1 + k0, lb1);
    __syncthreads();
    const f16x8* As8 = (const f16x8*)As;
    const f16x8* Bs8 = (const f16x8*)Bs;
    f16x8 aF[4], bF[4];
#pragma unroll
    for (int mt = 0; mt < 4; mt++) aF[mt] = As8[(wm + mt*16 + lr)*4 + quad];
#pragma unroll
    for (int nt = 0; nt < 4; nt++) bF[nt] = Bs8[(wn + nt*16 + lr)*4 + quad];
#pragma unroll
    for (int mt = 0; mt < 4; mt++)
#pragma unroll
      for (int nt = 0; nt < 4; nt++)
        acc[mt][nt] = __builtin_amdgcn_mfma_f32_16x16x32_f16(aF[mt], bF[nt], acc[mt][nt], 0, 0, 0);
    __syncthreads();
  }
#pragma unroll
  for (int mt = 0; mt < 4; mt++)
#pragma unroll
    for (int nt = 0; nt < 4; nt++){
      const int colb = col0 + wn + nt*16 + lr;
      const float bb = bias[colb];
#pragma unroll
      for (int r = 0; r < 4; r++){
        const long rr = row0 + wm + mt*16 + quad*4 + r;
        if (rr < N_TOK) C[rr*DIMD + colb] = acc[mt][nt][r] + bb;   // fp32 output
      }
    }
}

// ---------------- rmsnorm + relu + eps, in-place on qb and kb ----------------
__global__ __launch_bounds__(256) void norm_k(u16* __restrict__ qb, u16* __restrict__ kb,
                                              const float* __restrict__ nqw, const float* __restrict__ nkw){
  __shared__ float red[4];
  __shared__ float s_scale;
  const int n = blockIdx.x, t = threadIdx.x, lane = t&63, wv = t>>6;
  u16* bufs[2]; bufs[0] = qb; bufs[1] = kb;
  const float* wgts[2]; wgts[0] = nqw; wgts[1] = nkw;
  for (int pass = 0; pass < 2; pass++){
    u16* row = bufs[pass] + (long)n*DIMD;
    const float* wgt = wgts[pass];
    float v[6];
    float ssq = 0.f;
#pragma unroll
    for (int i = 0; i < 6; i++){ v[i] = h2f(row[t + i*256]); ssq += v[i]*v[i]; }
#pragma unroll
    for (int o = 32; o > 0; o >>= 1) ssq += __shfl_down(ssq, o);
    if (lane == 0) red[wv] = ssq;
    __syncthreads();
    if (t == 0) s_scale = rsqrtf((red[0]+red[1]+red[2]+red[3])/(float)DIMD + EPSF);
    __syncthreads();
    const float sc = s_scale;
#pragma unroll
    for (int i = 0; i < 6; i++){
      float r = fmaxf(v[i]*sc*wgt[t + i*256], 0.f) + EPSF;
      row[t + i*256] = f2h(r);
    }
    __syncthreads();
  }
}

// ---------------- ksum[h,b,d] = sum_p k_normed ----------------
__global__ __launch_bounds__(128) void ksum_k(const u16* __restrict__ kb, float* __restrict__ ksum){
  const int hb = blockIdx.x; const int h = hb/NBLK, b = hb%NBLK; const int d = threadIdx.x;
  float s = 0.f;
  for (int p = 0; p < PBLK; p++)
    s += h2f(kb[(long)tok_of(b, p)*DIMD + h*HD + d]);
  ksum[(long)hb*HD + d] = s;
}

// ---------------- qk[h,b,p] = q_normed . ksum ----------------
__global__ __launch_bounds__(128) void qk_k(const u16* __restrict__ qb, const float* __restrict__ ksum,
                                            float* __restrict__ qk){
  __shared__ float ks[HD];
  const int hb = blockIdx.x, h = hb/NBLK, b = hb%NBLK, t = threadIdx.x;
  ks[t] = ksum[(long)hb*HD + t];
  __syncthreads();
  if (t < PBLK){
    const u16* row = qb + (long)tok_of(b, t)*DIMD + h*HD;
    float s = 0.f;
#pragma unroll
    for (int d8 = 0; d8 < 16; d8++){
      int4 v4 = *(const int4*)(row + d8*8);
      const u16* pv = (const u16*)&v4;
#pragma unroll
      for (int j = 0; j < 8; j++) s += h2f(pv[j])*ks[d8*8 + j];
    }
    qk[(long)hb*PBLK + t] = s;
  }
}

// ---------------- norm[h,o,p] = sum_i W[o,i]*qk[h,i,p] + eps ----------------
__global__ __launch_bounds__(128) void mixqk_k(const float* __restrict__ qk, const float* __restrict__ wblk,
                                               float* __restrict__ nrm){
  const int ho = blockIdx.x, h = ho/NBLK, o = ho%NBLK, t = threadIdx.x;
  if (t >= PBLK) return;
  float s = 0.f;
  for (int i = 0; i < NBLK; i++) s += wblk[o*NBLK + i]*qk[((long)h*NBLK + i)*PBLK + t];
  nrm[(long)ho*PBLK + t] = s + EPSF;
}

// ---------------- kv1[h,b][e*128+d] = sum_p rope(K)[p,d]*V[p,e]  (RoPE fused in staging) ----------------
__global__ __launch_bounds__(256) void kv_k(const u16* __restrict__ kb, const u16* __restrict__ vb,
                                            const float* __restrict__ fcos, const float* __restrict__ fsin,
                                            u16* __restrict__ kv1){
  __shared__ u16 Ap[4][128][32];   // A = V^T : Ap[p>>5][e][p&31] = V[p,e]
  __shared__ u16 Bp[4][128][32];   // B = Kr^T: Bp[p>>5][d][p&31] = rope(K)[p,d]
  const int hb = blockIdx.x, h = hb/NBLK, b = hb%NBLK, t = threadIdx.x;
  for (int idx = t; idx < 128*64; idx += 256){
    const int p = idx>>6, cc = idx&63;
    u16 v0=0, v1=0, r0=0, r1=0;
    if (p < PBLK){
      int tok, f, hh, ww; tok_pos(b, p, tok, f, hh, ww);
      const long tb = (long)tok*DIMD + h*HD + 2*cc;
      const u32 vv = *(const u32*)&vb[tb];
      const u32 kk = *(const u32*)&kb[tb];
      const int pos = (cc < 22) ? f : (cc < 43 ? hh : ww);
      const float cv = fcos[pos*CCH + cc], sv = fsin[pos*CCH + cc];
      const float x0 = h2f((u16)kk), x1 = h2f((u16)(kk>>16));
      v0 = (u16)vv; v1 = (u16)(vv>>16);
      r0 = f2h(x0*cv - x1*sv); r1 = f2h(x0*sv + x1*cv);
    }
    const int kp = p>>5, j = p&31;
    Ap[kp][2*cc][j] = v0; Ap[kp][2*cc+1][j] = v1;
    Bp[kp][2*cc][j] = r0; Bp[kp][2*cc+1][j] = r1;
  }
  __syncthreads();
  const int wave = t>>6, lane = t&63, lr = lane&15, quad = lane>>4;
  const int wm = (wave&1)*64, wn = (wave>>1)*64;
  f32x4 acc[4][4] = {};
#pragma unroll
  for (int kp = 0; kp < 4; kp++){
    f16x8 aF[4], bF[4];
#pragma unroll
    for (int mt = 0; mt < 4; mt++) aF[mt] = *(const f16x8*)&Ap[kp][wm + mt*16 + lr][quad*8];
#pragma unroll
    for (int nt = 0; nt < 4; nt++) bF[nt] = *(const f16x8*)&Bp[kp][wn + nt*16 + lr][quad*8];
#pragma unroll
    for (int mt = 0; mt < 4; mt++)
#pragma unroll
      for (int nt = 0; nt < 4; nt++)
        acc[mt][nt] = __builtin_amdgcn_mfma_f32_16x16x32_f16(aF[mt], bF[nt], acc[mt][nt], 0, 0, 0);
  }
  u16* outp = kv1 + (long)hb*HD*HD;   // D[e,d] stored at [e*128+d] == kv[d,e]
#pragma unroll
  for (int mt = 0; mt < 4; mt++)
#pragma unroll
    for (int nt = 0; nt < 4; nt++)
#pragma unroll
      for (int r = 0; r < 4; r++)
        outp[(wm + mt*16 + quad*4 + r)*HD + wn + nt*16 + lr] = f2h(acc[mt][nt][r]);
}

// ---------------- kv2[h,o,:] = sum_i W[o,i]*kv1[h,i,:] ----------------
__global__ __launch_bounds__(256) void mix_k(const u16* __restrict__ kv1, const float* __restrict__ wblk,
                                             u16* __restrict__ kv2){
  __shared__ float X[NBLK][64];
  const int h = blockIdx.x >> 8, chunk = blockIdx.x & 255, t = threadIdx.x;
  const long base = (long)h*NBLK*HD*HD + chunk*64;
  for (int idx = t; idx < NBLK*64; idx += 256){
    const int i = idx>>6, de = idx&63;
    X[i][de] = h2f(kv1[base + (long)i*HD*HD + de]);
  }
  __syncthreads();
  const int de = t&63, og = t>>6;
  for (int o = og; o < NBLK; o += 4){
    const float* wr = wblk + o*NBLK;
    float s = 0.f;
    for (int i = 0; i < NBLK; i++) s += wr[i]*X[i][de];
    kv2[base + (long)o*HD*HD + de] = f2h(s);
  }
}

// ---------------- attn: Out[p,e] = (sum_d rope(Q)[p,d]*kv[d,e]) / norm[p]  (RoPE fused) ----------------
// aout == qb is safe: block (h,o) reads exactly the region it writes; reads complete
// before __syncthreads; regions disjoint across blocks.
__global__ __launch_bounds__(256) void attn_k(const u16* __restrict__ qb, const u16* __restrict__ kv2,
                                              const float* __restrict__ fcos, const float* __restrict__ fsin,
                                              const float* __restrict__ nrm, u16* __restrict__ aout){
  __shared__ u16 Ap[4][128][32];   // A: Ap[d>>5][p][d&31] = rope(Q)[p,d]
  __shared__ u16 Bp[4][128][32];   // B: Bp[d>>5][e][d&31] = kv[d,e]  (kv2 stored [e*128+d])
  const int ho = blockIdx.x, h = ho/NBLK, o = ho%NBLK, t = threadIdx.x;
  for (int idx = t; idx < 128*64; idx += 256){
    const int p = idx>>6, cc = idx&63;
    u32 w = 0;
    if (p < PBLK){
      int tok, f, hh, ww; tok_pos(o, p, tok, f, hh, ww);
      const u32 qq = *(const u32*)&qb[(long)tok*DIMD + h*HD + 2*cc];
      const int pos = (cc < 22) ? f : (cc < 43 ? hh : ww);
      const float cv = fcos[pos*CCH + cc], sv = fsin[pos*CCH + cc];
      const float x0 = h2f((u16)qq), x1 = h2f((u16)(qq>>16));
      w = (u32)f2h(x0*cv - x1*sv) | ((u32)f2h(x0*sv + x1*cv) << 16);
    }
    *(u32*)&Ap[(2*cc)>>5][p][(2*cc)&31] = w;
  }
  const u16* kv2p = kv2 + (long)ho*HD*HD;
  for (int idx = t; idx < 128*16; idx += 256){
    const int e = idx>>4, d8 = (idx&15)*8;
    int4 vv = *(const int4*)&kv2p[e*HD + d8];
    *(int4*)&Bp[d8>>5][e][d8&31] = vv;
  }
  __syncthreads();
  const int wave = t>>6, lane = t&63, lr = lane&15, quad = lane>>4;
  const int wm = (wave&1)*64, wn = (wave>>1)*64;
  f32x4 acc[4][4] = {};
#pragma unroll
  for (int kp = 0; kp < 4; kp++){
    f16x8 aF[4], bF[4];
#pragma unroll
    for (int mt = 0; mt < 4; mt++) aF[mt] = *(const f16x8*)&Ap[kp][wm + mt*16 + lr][quad*8];
#pragma unroll
    for (int nt = 0; nt < 4; nt++) bF[nt] = *(const f16x8*)&Bp[kp][wn + nt*16 + lr][quad*8];
#pragma unroll
    for (int mt = 0; mt < 4; mt++)
#pragma unroll
      for (int nt = 0; nt < 4; nt++)
        acc[mt][nt] = __builtin_amdgcn_mfma_f32_16x16x32_f16(aF[mt], bF[nt], acc[mt][nt], 0, 0, 0);
  }
#pragma unroll
  for (int mt = 0; mt < 4; mt++)
#pragma unroll
    for (int r = 0; r < 4; r++){
      const int p = wm + mt*16 + quad*4 + r;
      if (p >= PBLK) continue;
      const float inv = 1.0f / nrm[(long)ho*PBLK + p];
      const long tb = (long)tok_of(o, p)*DIMD + h*HD;
#pragma unroll
      for (int nt = 0; nt < 4; nt++)
        aout[tb + wn + nt*16 + lr] = f2h(acc[mt][nt][r]*inv);
    }
}

// ---------------- launch ----------------
extern "C" void kernel_launch(void* const* d_in, const int* in_sizes, int n_in,
                              void* d_out, int out_size, void* d_ws, size_t ws_size,
                              hipStream_t stream){
  const float* x    = (const float*)d_in[0];
  const float* fcos = (const float*)d_in[3];
  const float* fsin = (const float*)d_in[4];
  const float* wq   = (const float*)d_in[5];
  const float* bq   = (const float*)d_in[6];
  const float* wk   = (const float*)d_in[7];
  const float* bk   = (const float*)d_in[8];
  const float* wv   = (const float*)d_in[9];
  const float* bv   = (const float*)d_in[10];
  const float* wo   = (const float*)d_in[11];
  const float* bo   = (const float*)d_in[12];
  const float* nqw  = (const float*)d_in[13];
  const float* nkw  = (const float*)d_in[14];
  float* out = (float*)d_out;   // reference output dtype is fp32
  (void)in_sizes; (void)n_in; (void)out_size; (void)ws_size;

  char* ws = (char*)d_ws; size_t off = 0;
  auto alloc = [&](size_t b)->void*{ void* p = ws + off; off += (b + 255) & ~(size_t)255; return p; };
  const size_t SQ = (size_t)DIMD*DIMD;
  u16*   wqkvb = (u16*)  alloc(3*SQ*2);                     // 14.2 MB (fp16)
  u16*   wob   = (u16*)  alloc(SQ*2);                       //  4.7 MB (fp16)
  float* bqkv  = (float*)alloc((size_t)3*DIMD*4);
  float* wblk  = (float*)alloc((size_t)NBLK*NBLK*4);
  u16*   qb    = (u16*)  alloc((size_t)MPAD*DIMD*2);        // 55.4 MB (later: attn output)
  u16*   kb    = (u16*)  alloc((size_t)MPAD*DIMD*2);        // 55.4 MB (dead after kv_k)
  u16*   vb    = (u16*)  alloc((size_t)MPAD*DIMD*2);        // 55.4 MB (dead after kv_k)
  u16*   kv1   = (u16*)  alloc((size_t)NHH*NBLK*HD*HD*2);   // 59.0 MB
  float* ksum  = (float*)alloc((size_t)NHH*NBLK*HD*4);      //  0.9 MB
  float* qk    = (float*)alloc((size_t)NHH*NBLK*PBLK*4);    //  0.9 MB
  float* nrm   = (float*)alloc((size_t)NHH*NBLK*PBLK*4);    //  0.9 MB
  u16*   kv2   = kb;    // alias over [kb..vb) — both dead before mix_k writes
  u16*   xh    = kv1;   // alias: xh (55.4 MB) lives in kv1's region; dead before kv_k writes kv1
  // total fresh: ~247 MB

  conv_w_k<<<9216, 256, 0, stream>>>(wq, wk, wv, wo, bq, bk, bv, wqkvb, wob, bqkv);
  wblk_k<<<1, 256, 0, stream>>>(wblk);
  conv_x_k<<<(MPAD*DIMD/8 + 255)/256, 256, 0, stream>>>(x, xh);
  gemm_qkv<<<dim3(QKVN/128, MPAD/128), 256, 0, stream>>>(xh, wqkvb, bqkv, qb, kb, vb);
  norm_k<<<N_TOK, 256, 0, stream>>>(qb, kb, nqw, nkw);
  ksum_k<<<NHH*NBLK, 128, 0, stream>>>(kb, ksum);
  qk_k<<<NHH*NBLK, 128, 0, stream>>>(qb, ksum, qk);
  mixqk_k<<<NHH*NBLK, 128, 0, stream>>>(qk, wblk, nrm);
  kv_k<<<NHH*NBLK, 256, 0, stream>>>(kb, vb, fcos, fsin, kv1);
  mix_k<<<NHH*256, 256, 0, stream>>>(kv1, wblk, kv2);
  attn_k<<<NHH*NBLK, 256, 0, stream>>>(qb, kv2, fcos, fsin, nrm, qb);  // output aliases qb
  gemm_bt<<<dim3(DIMD/128, MPAD/128), 256, 0, stream>>>(qb, wob, bo, out, DIMD);
}